// Round 1
// baseline (629.618 us; speedup 1.0000x reference)
//
#include <hip/hip_runtime.h>
#include <hip/hip_bf16.h>

// Problem constants
#define Bsz 4
#define SEQ 1024
#define DIM 512
#define HEADS 8
#define DIM_HEAD 64
#define ROWS (Bsz * SEQ)        // 4096
#define QKV3 (3 * DIM_HEAD)     // 192

// ---------------------------------------------------------------------------
// LayerNorm: one block per row of x [ROWS, 512]
// ---------------------------------------------------------------------------
__global__ __launch_bounds__(256) void ln_kernel(
    const float* __restrict__ x, const float* __restrict__ g,
    const float* __restrict__ beta, float* __restrict__ xn)
{
    int r = blockIdx.x;
    int t = threadIdx.x;
    const float* xr = x + (size_t)r * DIM;
    float v0 = xr[t], v1 = xr[t + 256];
    float s = v0 + v1, ss = v0 * v0 + v1 * v1;
    #pragma unroll
    for (int off = 32; off; off >>= 1) {
        s  += __shfl_xor(s, off);
        ss += __shfl_xor(ss, off);
    }
    __shared__ float rs[4], rss[4];
    int wave = t >> 6, lane = t & 63;
    if (lane == 0) { rs[wave] = s; rss[wave] = ss; }
    __syncthreads();
    s  = rs[0] + rs[1] + rs[2] + rs[3];
    ss = rss[0] + rss[1] + rss[2] + rss[3];
    float mu  = s * (1.0f / DIM);
    float var = ss * (1.0f / DIM) - mu * mu;
    float rstd = rsqrtf(var + 1e-5f);
    float* out = xn + (size_t)r * DIM;
    out[t]       = (v0 - mu) * rstd * g[t]       + beta[t];
    out[t + 256] = (v1 - mu) * rstd * g[t + 256] + beta[t + 256];
}

// ---------------------------------------------------------------------------
// Generic fp32 tiled GEMM: C = alpha * A @ op(B) + bias
// BM=BN=64, BK=32, 256 threads, 4x4 micro-tile. Dims must divide tiles.
// TRANS_B=1 means C[m][n] = sum_k A[m][k] * B[n][k]
// ---------------------------------------------------------------------------
template <int TRANS_B>
__global__ __launch_bounds__(256) void gemm_kernel(
    const float* __restrict__ A, const float* __restrict__ B,
    float* __restrict__ C, const float* __restrict__ bias,
    int M, int N, int K, int lda, int ldb, int ldc,
    long strideA, long strideB, long strideC, float alpha)
{
    int bz = blockIdx.z;
    A += (size_t)bz * strideA;
    B += (size_t)bz * strideB;
    C += (size_t)bz * strideC;

    const int BK = 32;
    __shared__ float As[BK][64 + 1];
    __shared__ float Bs[BK][64 + 1];

    int t = threadIdx.x;
    int block_m = blockIdx.y * 64;
    int block_n = blockIdx.x * 64;
    int tx = t & 15, ty = t >> 4;

    float acc[4][4] = {};

    for (int k0 = 0; k0 < K; k0 += BK) {
        { // A tile 64x32 (row-major src, store transposed)
            int kk = t & 31;
            int m0 = t >> 5;
            #pragma unroll
            for (int s = 0; s < 8; ++s) {
                int m = m0 + s * 8;
                As[kk][m] = A[(size_t)(block_m + m) * lda + k0 + kk];
            }
        }
        if (TRANS_B) {
            int kk = t & 31;
            int n0 = t >> 5;
            #pragma unroll
            for (int s = 0; s < 8; ++s) {
                int n = n0 + s * 8;
                Bs[kk][n] = B[(size_t)(block_n + n) * ldb + k0 + kk];
            }
        } else {
            int n = t & 63;
            int kb = t >> 6;
            #pragma unroll
            for (int s = 0; s < 8; ++s) {
                int kk = kb + s * 4;
                Bs[kk][n] = B[(size_t)(k0 + kk) * ldb + block_n + n];
            }
        }
        __syncthreads();
        #pragma unroll
        for (int kk = 0; kk < BK; ++kk) {
            float a[4], b[4];
            #pragma unroll
            for (int i = 0; i < 4; ++i) a[i] = As[kk][ty * 4 + i];
            #pragma unroll
            for (int j = 0; j < 4; ++j) b[j] = Bs[kk][tx * 4 + j];
            #pragma unroll
            for (int i = 0; i < 4; ++i)
                #pragma unroll
                for (int j = 0; j < 4; ++j) acc[i][j] += a[i] * b[j];
        }
        __syncthreads();
    }

    #pragma unroll
    for (int i = 0; i < 4; ++i) {
        int m = block_m + ty * 4 + i;
        #pragma unroll
        for (int j = 0; j < 4; ++j) {
            int n = block_n + tx * 4 + j;
            float v = acc[i][j] * alpha;
            if (bias) v += bias[n];
            C[(size_t)m * ldc + n] = v;
        }
    }
}

// ---------------------------------------------------------------------------
// Fused LML k-softmax solve + PV accumulate.
// One block (256 threads) per row r = b*SEQ + i of dots [ROWS, 1024].
// Solves sum_j sigmoid(x_j + nu_n) = n (n=1..8) via 28-iter lockstep
// bisection (bracket width ~42 -> nu error < 1.6e-7), then computes
// o_n[d] = sum_j sigmoid(x_j+nu_n) * v[j][d] and writes head differences
// y[r][h*64+d] = o_{h+1}[d] - o_h[d].
// ---------------------------------------------------------------------------
__global__ __launch_bounds__(256) void solve_pv_kernel(
    const float* __restrict__ dots, const float* __restrict__ qkv,
    float* __restrict__ y)
{
    int r = blockIdx.x;
    int b = r >> 10;
    int t = threadIdx.x;
    int wave = t >> 6, lane = t & 63;

    const float* x = dots + (size_t)r * SEQ;

    __shared__ float p_lds[8][1024];
    __shared__ float red[4][8];
    __shared__ float o_lds[8][64];
    __shared__ float mxmn[4][2];

    // load 4 elements per thread, coalesced
    float xr[4], e[4];
    #pragma unroll
    for (int s = 0; s < 4; ++s) xr[s] = x[t + 256 * s];

    // row max/min for the bisection bracket
    float mx = fmaxf(fmaxf(xr[0], xr[1]), fmaxf(xr[2], xr[3]));
    float mn = fminf(fminf(xr[0], xr[1]), fminf(xr[2], xr[3]));
    #pragma unroll
    for (int off = 32; off; off >>= 1) {
        mx = fmaxf(mx, __shfl_xor(mx, off));
        mn = fminf(mn, __shfl_xor(mn, off));
    }
    if (lane == 0) { mxmn[wave][0] = mx; mxmn[wave][1] = mn; }
    __syncthreads();
    mx = fmaxf(fmaxf(mxmn[0][0], mxmn[1][0]), fmaxf(mxmn[2][0], mxmn[3][0]));
    mn = fminf(fminf(mxmn[0][1], mxmn[1][1]), fminf(mxmn[2][1], mxmn[3][1]));

    float lo0 = -mx - 20.0f, hi0 = -mn + 20.0f;
    float lo[8], hi[8];
    #pragma unroll
    for (int n = 0; n < 8; ++n) { lo[n] = lo0; hi[n] = hi0; }

    #pragma unroll
    for (int s = 0; s < 4; ++s) e[s] = __expf(xr[s]);

    for (int it = 0; it < 28; ++it) {
        float S[8];
        #pragma unroll
        for (int n = 0; n < 8; ++n) {
            float mid = 0.5f * (lo[n] + hi[n]);
            float tn = __expf(mid);
            float sn = 0.0f;
            #pragma unroll
            for (int s = 0; s < 4; ++s) {
                float u = e[s] * tn;
                sn += u * __builtin_amdgcn_rcpf(1.0f + u);
            }
            S[n] = sn;
        }
        #pragma unroll
        for (int n = 0; n < 8; ++n)
            #pragma unroll
            for (int off = 32; off; off >>= 1) S[n] += __shfl_xor(S[n], off);
        if (lane == 0) {
            #pragma unroll
            for (int n = 0; n < 8; ++n) red[wave][n] = S[n];
        }
        __syncthreads();
        #pragma unroll
        for (int n = 0; n < 8; ++n) {
            float tot = red[0][n] + red[1][n] + red[2][n] + red[3][n];
            float mid = 0.5f * (lo[n] + hi[n]);
            if (tot < (float)(n + 1)) lo[n] = mid; else hi[n] = mid;
        }
        __syncthreads();
    }

    // final p_n into LDS
    #pragma unroll
    for (int n = 0; n < 8; ++n) {
        float nu = 0.5f * (lo[n] + hi[n]);
        float tn = __expf(nu);
        #pragma unroll
        for (int s = 0; s < 4; ++s) {
            float u = e[s] * tn;
            p_lds[n][t + 256 * s] = u * __builtin_amdgcn_rcpf(1.0f + u);
        }
    }
    __syncthreads();

    // PV: wave w handles n = w and w+4; lane = d
    int d = lane, n0 = wave;
    const float* vbase = qkv + ((size_t)b * SEQ) * QKV3 + 2 * DIM_HEAD + d;
    float acc0 = 0.0f, acc1 = 0.0f;
    #pragma unroll 4
    for (int j = 0; j < SEQ; ++j) {
        float vv = vbase[(size_t)j * QKV3];
        acc0 += p_lds[n0][j] * vv;
        acc1 += p_lds[n0 + 4][j] * vv;
    }
    o_lds[n0][d] = acc0;
    o_lds[n0 + 4][d] = acc1;
    __syncthreads();

    // head differences -> y[r][h*64+d]
    float* yr = y + (size_t)r * (HEADS * DIM_HEAD);
    #pragma unroll
    for (int s = 0; s < 2; ++s) {
        int c = t + 256 * s;
        int h = c >> 6, dd = c & 63;
        float val = o_lds[h][dd] - (h ? o_lds[h - 1][dd] : 0.0f);
        yr[c] = val;
    }
}

// ---------------------------------------------------------------------------
extern "C" void kernel_launch(void* const* d_in, const int* in_sizes, int n_in,
                              void* d_out, int out_size, void* d_ws, size_t ws_size,
                              hipStream_t stream)
{
    const float* x       = (const float*)d_in[0];
    const float* ln_g    = (const float*)d_in[1];
    const float* ln_b    = (const float*)d_in[2];
    const float* w_qkv   = (const float*)d_in[3];
    const float* w_out   = (const float*)d_in[4];
    const float* b_out   = (const float*)d_in[5];
    float* out = (float*)d_out;

    // workspace layout (floats): xn[ROWS*DIM] | qkv[ROWS*192] | dots[4*1024*1024]
    // y reuses xn (dead after the qkv GEMM). Total ~28.3 MB.
    float* xn   = (float*)d_ws;
    float* qkv  = xn + (size_t)ROWS * DIM;
    float* dots = qkv + (size_t)ROWS * QKV3;
    float* y    = xn;  // reuse

    // 1) LayerNorm
    ln_kernel<<<ROWS, 256, 0, stream>>>(x, ln_g, ln_b, xn);

    // 2) qkv = xn @ w_qkv   [4096,512]x[512,192]
    gemm_kernel<0><<<dim3(QKV3 / 64, ROWS / 64, 1), 256, 0, stream>>>(
        xn, w_qkv, qkv, nullptr,
        ROWS, QKV3, DIM, DIM, QKV3, QKV3, 0, 0, 0, 1.0f);

    // 3) dots[b] = 0.125 * q[b] @ k[b]^T   batched [1024,64]x[64,1024]
    gemm_kernel<1><<<dim3(SEQ / 64, SEQ / 64, Bsz), 256, 0, stream>>>(
        qkv, qkv + DIM_HEAD, dots, nullptr,
        SEQ, SEQ, DIM_HEAD, QKV3, QKV3, SEQ,
        (long)SEQ * QKV3, (long)SEQ * QKV3, (long)SEQ * SEQ, 0.125f);

    // 4) fused LML solve + PV + head differences -> y [4096, 512]
    solve_pv_kernel<<<ROWS, 256, 0, stream>>>(dots, qkv, y);

    // 5) out = y @ w_out + b_out   [4096,512]x[512,512]
    gemm_kernel<0><<<dim3(DIM / 64, ROWS / 64, 1), 256, 0, stream>>>(
        y, w_out, out, b_out,
        ROWS, DIM, DIM, DIM, DIM, DIM, 0, 0, 0, 1.0f);
}

// Round 3
// 406.516 us; speedup vs baseline: 1.5488x; 1.5488x over previous
//
#include <hip/hip_runtime.h>
#include <hip/hip_bf16.h>

// Problem constants
#define Bsz 4
#define SEQ 1024
#define DIM 512
#define HEADS 8
#define DIM_HEAD 64
#define ROWS (Bsz * SEQ)        // 4096
#define QKV3 (3 * DIM_HEAD)     // 192

// ---------------------------------------------------------------------------
// LayerNorm: one block per row of x [ROWS, 512]
// ---------------------------------------------------------------------------
__global__ __launch_bounds__(256) void ln_kernel(
    const float* __restrict__ x, const float* __restrict__ g,
    const float* __restrict__ beta, float* __restrict__ xn)
{
    int r = blockIdx.x;
    int t = threadIdx.x;
    const float* xr = x + (size_t)r * DIM;
    float v0 = xr[t], v1 = xr[t + 256];
    float s = v0 + v1, ss = v0 * v0 + v1 * v1;
    #pragma unroll
    for (int off = 32; off; off >>= 1) {
        s  += __shfl_xor(s, off);
        ss += __shfl_xor(ss, off);
    }
    __shared__ float rs[4], rss[4];
    int wave = t >> 6, lane = t & 63;
    if (lane == 0) { rs[wave] = s; rss[wave] = ss; }
    __syncthreads();
    s  = rs[0] + rs[1] + rs[2] + rs[3];
    ss = rss[0] + rss[1] + rss[2] + rss[3];
    float mu  = s * (1.0f / DIM);
    float var = ss * (1.0f / DIM) - mu * mu;
    float rstd = rsqrtf(var + 1e-5f);
    float* out = xn + (size_t)r * DIM;
    out[t]       = (v0 - mu) * rstd * g[t]       + beta[t];
    out[t + 256] = (v1 - mu) * rstd * g[t + 256] + beta[t + 256];
}

// ---------------------------------------------------------------------------
// Generic fp32 tiled GEMM: C = alpha * A @ op(B) + bias
// ---------------------------------------------------------------------------
template <int TRANS_B>
__global__ __launch_bounds__(256) void gemm_kernel(
    const float* __restrict__ A, const float* __restrict__ B,
    float* __restrict__ C, const float* __restrict__ bias,
    int M, int N, int K, int lda, int ldb, int ldc,
    long strideA, long strideB, long strideC, float alpha)
{
    int bz = blockIdx.z;
    A += (size_t)bz * strideA;
    B += (size_t)bz * strideB;
    C += (size_t)bz * strideC;

    const int BK = 32;
    __shared__ float As[BK][64 + 1];
    __shared__ float Bs[BK][64 + 1];

    int t = threadIdx.x;
    int block_m = blockIdx.y * 64;
    int block_n = blockIdx.x * 64;
    int tx = t & 15, ty = t >> 4;

    float acc[4][4] = {};

    for (int k0 = 0; k0 < K; k0 += BK) {
        { // A tile 64x32 (row-major src, store transposed)
            int kk = t & 31;
            int m0 = t >> 5;
            #pragma unroll
            for (int s = 0; s < 8; ++s) {
                int m = m0 + s * 8;
                As[kk][m] = A[(size_t)(block_m + m) * lda + k0 + kk];
            }
        }
        if (TRANS_B) {
            int kk = t & 31;
            int n0 = t >> 5;
            #pragma unroll
            for (int s = 0; s < 8; ++s) {
                int n = n0 + s * 8;
                Bs[kk][n] = B[(size_t)(block_n + n) * ldb + k0 + kk];
            }
        } else {
            int n = t & 63;
            int kb = t >> 6;
            #pragma unroll
            for (int s = 0; s < 8; ++s) {
                int kk = kb + s * 4;
                Bs[kk][n] = B[(size_t)(k0 + kk) * ldb + block_n + n];
            }
        }
        __syncthreads();
        #pragma unroll
        for (int kk = 0; kk < BK; ++kk) {
            float a[4], b[4];
            #pragma unroll
            for (int i = 0; i < 4; ++i) a[i] = As[kk][ty * 4 + i];
            #pragma unroll
            for (int j = 0; j < 4; ++j) b[j] = Bs[kk][tx * 4 + j];
            #pragma unroll
            for (int i = 0; i < 4; ++i)
                #pragma unroll
                for (int j = 0; j < 4; ++j) acc[i][j] += a[i] * b[j];
        }
        __syncthreads();
    }

    #pragma unroll
    for (int i = 0; i < 4; ++i) {
        int m = block_m + ty * 4 + i;
        #pragma unroll
        for (int j = 0; j < 4; ++j) {
            int n = block_n + tx * 4 + j;
            float v = acc[i][j] * alpha;
            if (bias) v += bias[n];
            C[(size_t)m * ldc + n] = v;
        }
    }
}

// ---------------------------------------------------------------------------
// LML solve: ONE WAVE PER ROW, no barriers, no LDS.
// Tight bracket: nu* in [logit(N/1024)-mx, logit(N/1024)-mn]  (width mx-mn)
//   proof: S(nu) <= 1024*sigmoid(mx+nu)  =>  S(logit-mx) <= N  (lower bound)
//          S(nu) >= 1024*sigmoid(mn+nu)  =>  S(logit-mn) >= N  (upper bound)
// 12 lockstep bisections (width -> ~2.5/4096 = 6e-4) + 5 guarded Newton.
// Worst case (all Newton rejected): nu err ~ 2.5/2^17 = 1.9e-5. Typical:
// Newton converges to fp32 noise. Butterfly shfl_xor keeps lanes identical.
// ---------------------------------------------------------------------------
__global__ __launch_bounds__(256) void solve_kernel(
    const float* __restrict__ dots, float* __restrict__ nu_out)
{
    int wave = threadIdx.x >> 6;
    int lane = threadIdx.x & 63;
    int r = blockIdx.x * 4 + wave;
    const float* x = dots + (size_t)r * SEQ;

    // 16 elements per lane via 4x float4 (row is 16B-aligned)
    float e[16];
    #pragma unroll
    for (int s = 0; s < 4; ++s) {
        float4 v = *(const float4*)(x + lane * 4 + 256 * s);
        e[4 * s + 0] = v.x; e[4 * s + 1] = v.y;
        e[4 * s + 2] = v.z; e[4 * s + 3] = v.w;
    }
    float mx = e[0], mn = e[0];
    #pragma unroll
    for (int s = 1; s < 16; ++s) { mx = fmaxf(mx, e[s]); mn = fminf(mn, e[s]); }
    #pragma unroll
    for (int off = 32; off; off >>= 1) {
        mx = fmaxf(mx, __shfl_xor(mx, off));
        mn = fminf(mn, __shfl_xor(mn, off));
    }
    #pragma unroll
    for (int s = 0; s < 16; ++s) e[s] = __expf(e[s]);

    float lo[8], hi[8];
    #pragma unroll
    for (int n = 0; n < 8; ++n) {
        float lgt = __logf((float)(n + 1) / (float)(SEQ - (n + 1)));
        lo[n] = lgt - mx;
        hi[n] = lgt - mn;
    }

    // ---- 12 bisection iterations ----
    for (int it = 0; it < 12; ++it) {
        float S[8];
        #pragma unroll
        for (int n = 0; n < 8; ++n) {
            float mid = 0.5f * (lo[n] + hi[n]);
            float tn = __expf(mid);
            float sn = 0.0f;
            #pragma unroll
            for (int s = 0; s < 16; ++s) {
                float u = e[s] * tn;
                sn += u * __builtin_amdgcn_rcpf(1.0f + u);
            }
            S[n] = sn;
        }
        #pragma unroll
        for (int n = 0; n < 8; ++n) {
            #pragma unroll
            for (int off = 32; off; off >>= 1) S[n] += __shfl_xor(S[n], off);
            float mid = 0.5f * (lo[n] + hi[n]);
            if (S[n] < (float)(n + 1)) lo[n] = mid; else hi[n] = mid;
        }
    }

    float nu[8];
    #pragma unroll
    for (int n = 0; n < 8; ++n) nu[n] = 0.5f * (lo[n] + hi[n]);

    // ---- 5 guarded Newton iterations ----
    for (int it = 0; it < 5; ++it) {
        float S[8], Sp[8];
        #pragma unroll
        for (int n = 0; n < 8; ++n) {
            float tn = __expf(nu[n]);
            float sn = 0.0f, spn = 0.0f;
            #pragma unroll
            for (int s = 0; s < 16; ++s) {
                float u = e[s] * tn;
                float p = u * __builtin_amdgcn_rcpf(1.0f + u);
                sn += p;
                spn = fmaf(p, -p, spn + p);   // += p - p*p
            }
            S[n] = sn; Sp[n] = spn;
        }
        #pragma unroll
        for (int n = 0; n < 8; ++n) {
            #pragma unroll
            for (int off = 32; off; off >>= 1) {
                S[n]  += __shfl_xor(S[n], off);
                Sp[n] += __shfl_xor(Sp[n], off);
            }
            if (S[n] < (float)(n + 1)) lo[n] = nu[n]; else hi[n] = nu[n];
            float step = ((float)(n + 1) - S[n]) * __builtin_amdgcn_rcpf(Sp[n]);
            float cand = nu[n] + step;
            if (!(cand > lo[n] && cand < hi[n])) cand = 0.5f * (lo[n] + hi[n]);
            nu[n] = cand;
        }
    }

    // write nu[r][0..7]: all lanes hold identical values; lanes 0..7 store
    float myv = nu[0];
    #pragma unroll
    for (int n = 1; n < 8; ++n) if (lane == n) myv = nu[n];
    if (lane < 8) nu_out[(size_t)r * 8 + lane] = myv;
}

// ---------------------------------------------------------------------------
// PV: one block per row. Rebuild p_n(j) into fp32 LDS, then wave w computes
// o_n[d] for n = w, w+4 (lane = d), and head differences go to y.
// LDS p reads are wave-uniform addresses (broadcast, conflict-free).
// ---------------------------------------------------------------------------
__global__ __launch_bounds__(256) void pv_kernel(
    const float* __restrict__ dots, const float* __restrict__ nu_in,
    const float* __restrict__ qkv, float* __restrict__ y)
{
    int r = blockIdx.x;
    int b = r >> 10;
    int t = threadIdx.x;
    int wave = t >> 6, lane = t & 63;

    __shared__ float p_lds[8][1024];
    __shared__ float o_lds[8][64];

    const float* x = dots + (size_t)r * SEQ;

    float tn[8];
    #pragma unroll
    for (int n = 0; n < 8; ++n) tn[n] = __expf(nu_in[(size_t)r * 8 + n]);

    #pragma unroll
    for (int s = 0; s < 4; ++s) {
        int j = t + 256 * s;
        float ex = __expf(x[j]);
        #pragma unroll
        for (int n = 0; n < 8; ++n) {
            float u = ex * tn[n];
            p_lds[n][j] = u * __builtin_amdgcn_rcpf(1.0f + u);
        }
    }
    __syncthreads();

    int d = lane, n0 = wave;
    const float* vbase = qkv + ((size_t)b * SEQ) * QKV3 + 2 * DIM_HEAD + d;
    float acc0 = 0.0f, acc1 = 0.0f;
    for (int j = 0; j < SEQ; j += 4) {
        float4 pa = *(const float4*)&p_lds[n0][j];
        float4 pb = *(const float4*)&p_lds[n0 + 4][j];
        float v0 = vbase[(size_t)(j + 0) * QKV3];
        float v1 = vbase[(size_t)(j + 1) * QKV3];
        float v2 = vbase[(size_t)(j + 2) * QKV3];
        float v3 = vbase[(size_t)(j + 3) * QKV3];
        acc0 = fmaf(pa.x, v0, acc0); acc1 = fmaf(pb.x, v0, acc1);
        acc0 = fmaf(pa.y, v1, acc0); acc1 = fmaf(pb.y, v1, acc1);
        acc0 = fmaf(pa.z, v2, acc0); acc1 = fmaf(pb.z, v2, acc1);
        acc0 = fmaf(pa.w, v3, acc0); acc1 = fmaf(pb.w, v3, acc1);
    }
    o_lds[n0][d] = acc0;
    o_lds[n0 + 4][d] = acc1;
    __syncthreads();

    float* yr = y + (size_t)r * (HEADS * DIM_HEAD);
    #pragma unroll
    for (int s = 0; s < 2; ++s) {
        int c = t + 256 * s;
        int h = c >> 6, dd = c & 63;
        float val = o_lds[h][dd] - (h ? o_lds[h - 1][dd] : 0.0f);
        yr[c] = val;
    }
}

// ---------------------------------------------------------------------------
extern "C" void kernel_launch(void* const* d_in, const int* in_sizes, int n_in,
                              void* d_out, int out_size, void* d_ws, size_t ws_size,
                              hipStream_t stream)
{
    const float* x       = (const float*)d_in[0];
    const float* ln_g    = (const float*)d_in[1];
    const float* ln_b    = (const float*)d_in[2];
    const float* w_qkv   = (const float*)d_in[3];
    const float* w_out   = (const float*)d_in[4];
    const float* b_out   = (const float*)d_in[5];
    float* out = (float*)d_out;

    // ws: xn[ROWS*DIM] | qkv[ROWS*192] | dots[4M] | nu[ROWS*8]   (~28.5 MB)
    float* xn   = (float*)d_ws;
    float* qkv  = xn + (size_t)ROWS * DIM;
    float* dots = qkv + (size_t)ROWS * QKV3;
    float* nu   = dots + (size_t)Bsz * SEQ * SEQ;
    float* y    = xn;  // reuse (dead after qkv GEMM; rewritten by pv_kernel)

    // 1) LayerNorm
    ln_kernel<<<ROWS, 256, 0, stream>>>(x, ln_g, ln_b, xn);

    // 2) qkv = xn @ w_qkv
    gemm_kernel<0><<<dim3(QKV3 / 64, ROWS / 64, 1), 256, 0, stream>>>(
        xn, w_qkv, qkv, nullptr,
        ROWS, QKV3, DIM, DIM, QKV3, QKV3, 0, 0, 0, 1.0f);

    // 3) dots[b] = 0.125 * q[b] @ k[b]^T
    gemm_kernel<1><<<dim3(SEQ / 64, SEQ / 64, Bsz), 256, 0, stream>>>(
        qkv, qkv + DIM_HEAD, dots, nullptr,
        SEQ, SEQ, DIM_HEAD, QKV3, QKV3, SEQ,
        (long)SEQ * QKV3, (long)SEQ * QKV3, (long)SEQ * SEQ, 0.125f);

    // 4) LML solve (1 wave/row): nu[4096][8]
    solve_kernel<<<ROWS / 4, 256, 0, stream>>>(dots, nu);

    // 5) PV + head differences -> y
    pv_kernel<<<ROWS, 256, 0, stream>>>(dots, nu, qkv, y);

    // 6) out = y @ w_out + b_out
    gemm_kernel<0><<<dim3(DIM / 64, ROWS / 64, 1), 256, 0, stream>>>(
        y, w_out, out, b_out,
        ROWS, DIM, DIM, DIM, DIM, DIM, 0, 0, 0, 1.0f);
}

// Round 5
// 361.882 us; speedup vs baseline: 1.7398x; 1.1233x over previous
//
#include <hip/hip_runtime.h>
#include <hip/hip_bf16.h>

// Problem constants
#define Bsz 4
#define SEQ 1024
#define DIM 512
#define HEADS 8
#define DIM_HEAD 64
#define ROWS (Bsz * SEQ)        // 4096
#define QKV3 (3 * DIM_HEAD)     // 192

// ---------------------------------------------------------------------------
// LayerNorm: one block per row of x [ROWS, 512]
// ---------------------------------------------------------------------------
__global__ __launch_bounds__(256) void ln_kernel(
    const float* __restrict__ x, const float* __restrict__ g,
    const float* __restrict__ beta, float* __restrict__ xn)
{
    int r = blockIdx.x;
    int t = threadIdx.x;
    const float* xr = x + (size_t)r * DIM;
    float v0 = xr[t], v1 = xr[t + 256];
    float s = v0 + v1, ss = v0 * v0 + v1 * v1;
    #pragma unroll
    for (int off = 32; off; off >>= 1) {
        s  += __shfl_xor(s, off);
        ss += __shfl_xor(ss, off);
    }
    __shared__ float rs[4], rss[4];
    int wave = t >> 6, lane = t & 63;
    if (lane == 0) { rs[wave] = s; rss[wave] = ss; }
    __syncthreads();
    s  = rs[0] + rs[1] + rs[2] + rs[3];
    ss = rss[0] + rss[1] + rss[2] + rss[3];
    float mu  = s * (1.0f / DIM);
    float var = ss * (1.0f / DIM) - mu * mu;
    float rstd = rsqrtf(var + 1e-5f);
    float* out = xn + (size_t)r * DIM;
    out[t]       = (v0 - mu) * rstd * g[t]       + beta[t];
    out[t + 256] = (v1 - mu) * rstd * g[t + 256] + beta[t + 256];
}

// ---------------------------------------------------------------------------
// Generic fp32 tiled GEMM: C = alpha * A @ op(B) + bias
// ---------------------------------------------------------------------------
template <int TRANS_B>
__global__ __launch_bounds__(256) void gemm_kernel(
    const float* __restrict__ A, const float* __restrict__ B,
    float* __restrict__ C, const float* __restrict__ bias,
    int M, int N, int K, int lda, int ldb, int ldc,
    long strideA, long strideB, long strideC, float alpha)
{
    int bz = blockIdx.z;
    A += (size_t)bz * strideA;
    B += (size_t)bz * strideB;
    C += (size_t)bz * strideC;

    const int BK = 32;
    __shared__ float As[BK][64 + 1];
    __shared__ float Bs[BK][64 + 1];

    int t = threadIdx.x;
    int block_m = blockIdx.y * 64;
    int block_n = blockIdx.x * 64;
    int tx = t & 15, ty = t >> 4;

    float acc[4][4] = {};

    for (int k0 = 0; k0 < K; k0 += BK) {
        { // A tile 64x32 (row-major src, store transposed)
            int kk = t & 31;
            int m0 = t >> 5;
            #pragma unroll
            for (int s = 0; s < 8; ++s) {
                int m = m0 + s * 8;
                As[kk][m] = A[(size_t)(block_m + m) * lda + k0 + kk];
            }
        }
        if (TRANS_B) {
            int kk = t & 31;
            int n0 = t >> 5;
            #pragma unroll
            for (int s = 0; s < 8; ++s) {
                int n = n0 + s * 8;
                Bs[kk][n] = B[(size_t)(block_n + n) * ldb + k0 + kk];
            }
        } else {
            int n = t & 63;
            int kb = t >> 6;
            #pragma unroll
            for (int s = 0; s < 8; ++s) {
                int kk = kb + s * 4;
                Bs[kk][n] = B[(size_t)(k0 + kk) * ldb + block_n + n];
            }
        }
        __syncthreads();
        #pragma unroll
        for (int kk = 0; kk < BK; ++kk) {
            float a[4], b[4];
            #pragma unroll
            for (int i = 0; i < 4; ++i) a[i] = As[kk][ty * 4 + i];
            #pragma unroll
            for (int j = 0; j < 4; ++j) b[j] = Bs[kk][tx * 4 + j];
            #pragma unroll
            for (int i = 0; i < 4; ++i)
                #pragma unroll
                for (int j = 0; j < 4; ++j) acc[i][j] += a[i] * b[j];
        }
        __syncthreads();
    }

    #pragma unroll
    for (int i = 0; i < 4; ++i) {
        int m = block_m + ty * 4 + i;
        #pragma unroll
        for (int j = 0; j < 4; ++j) {
            int n = block_n + tx * 4 + j;
            float v = acc[i][j] * alpha;
            if (bias) v += bias[n];
            C[(size_t)m * ldc + n] = v;
        }
    }
}

// ---------------------------------------------------------------------------
// LML solve — ROUND-3 PROVEN VERSION (verbatim). One wave per row.
// Tight bracket: nu* in [logit(N/1024)-mx, logit(N/1024)-mn].
// 12 lockstep bisections + 5 guarded Newton evals.
// ---------------------------------------------------------------------------
__global__ __launch_bounds__(256) void solve_kernel(
    const float* __restrict__ dots, float* __restrict__ nu_out)
{
    int wave = threadIdx.x >> 6;
    int lane = threadIdx.x & 63;
    int r = blockIdx.x * 4 + wave;
    const float* x = dots + (size_t)r * SEQ;

    float e[16];
    #pragma unroll
    for (int s = 0; s < 4; ++s) {
        float4 v = *(const float4*)(x + lane * 4 + 256 * s);
        e[4 * s + 0] = v.x; e[4 * s + 1] = v.y;
        e[4 * s + 2] = v.z; e[4 * s + 3] = v.w;
    }
    float mx = e[0], mn = e[0];
    #pragma unroll
    for (int s = 1; s < 16; ++s) { mx = fmaxf(mx, e[s]); mn = fminf(mn, e[s]); }
    #pragma unroll
    for (int off = 32; off; off >>= 1) {
        mx = fmaxf(mx, __shfl_xor(mx, off));
        mn = fminf(mn, __shfl_xor(mn, off));
    }
    #pragma unroll
    for (int s = 0; s < 16; ++s) e[s] = __expf(e[s]);

    float lo[8], hi[8];
    #pragma unroll
    for (int n = 0; n < 8; ++n) {
        float lgt = __logf((float)(n + 1) / (float)(SEQ - (n + 1)));
        lo[n] = lgt - mx;
        hi[n] = lgt - mn;
    }

    // ---- 12 bisection iterations ----
    for (int it = 0; it < 12; ++it) {
        float S[8];
        #pragma unroll
        for (int n = 0; n < 8; ++n) {
            float mid = 0.5f * (lo[n] + hi[n]);
            float tn = __expf(mid);
            float sn = 0.0f;
            #pragma unroll
            for (int s = 0; s < 16; ++s) {
                float u = e[s] * tn;
                sn += u * __builtin_amdgcn_rcpf(1.0f + u);
            }
            S[n] = sn;
        }
        #pragma unroll
        for (int n = 0; n < 8; ++n) {
            #pragma unroll
            for (int off = 32; off; off >>= 1) S[n] += __shfl_xor(S[n], off);
            float mid = 0.5f * (lo[n] + hi[n]);
            if (S[n] < (float)(n + 1)) lo[n] = mid; else hi[n] = mid;
        }
    }

    float nu[8];
    #pragma unroll
    for (int n = 0; n < 8; ++n) nu[n] = 0.5f * (lo[n] + hi[n]);

    // ---- 5 guarded Newton iterations ----
    for (int it = 0; it < 5; ++it) {
        float S[8], Sp[8];
        #pragma unroll
        for (int n = 0; n < 8; ++n) {
            float tn = __expf(nu[n]);
            float sn = 0.0f, spn = 0.0f;
            #pragma unroll
            for (int s = 0; s < 16; ++s) {
                float u = e[s] * tn;
                float p = u * __builtin_amdgcn_rcpf(1.0f + u);
                sn += p;
                spn = fmaf(p, -p, spn + p);   // += p - p*p
            }
            S[n] = sn; Sp[n] = spn;
        }
        #pragma unroll
        for (int n = 0; n < 8; ++n) {
            #pragma unroll
            for (int off = 32; off; off >>= 1) {
                S[n]  += __shfl_xor(S[n], off);
                Sp[n] += __shfl_xor(Sp[n], off);
            }
            if (S[n] < (float)(n + 1)) lo[n] = nu[n]; else hi[n] = nu[n];
            float step = ((float)(n + 1) - S[n]) * __builtin_amdgcn_rcpf(Sp[n]);
            float cand = nu[n] + step;
            if (!(cand > lo[n] && cand < hi[n])) cand = 0.5f * (lo[n] + hi[n]);
            nu[n] = cand;
        }
    }

    float myv = nu[0];
    #pragma unroll
    for (int n = 1; n < 8; ++n) if (lane == n) myv = nu[n];
    if (lane < 8) nu_out[(size_t)r * 8 + lane] = myv;
}

// ---------------------------------------------------------------------------
// PV (round-4 restructure): one block per row. p stored pA[j][0..3] /
// pB[j][0..3] so the inner loop does 2 uniform (broadcast) float4 LDS reads
// per j. Wave w covers j in [256w, 256w+256) for ALL 8 heads -> V loaded
// exactly once per block (was 4x). Cross-wave reduce via LDS.
// ---------------------------------------------------------------------------
__global__ __launch_bounds__(256) void pv_kernel(
    const float* __restrict__ dots, const float* __restrict__ nu_in,
    const float* __restrict__ qkv, float* __restrict__ y)
{
    int r = blockIdx.x;
    int b = r >> 10;
    int t = threadIdx.x;
    int wave = t >> 6, lane = t & 63;

    __shared__ float pA[1024][4];     // heads 0..3   16 KB
    __shared__ float pB[1024][4];     // heads 4..7   16 KB
    __shared__ float ow[4][8][64];    // per-wave partials  8 KB

    const float* x = dots + (size_t)r * SEQ;

    float tn[8];
    #pragma unroll
    for (int n = 0; n < 8; ++n) tn[n] = __expf(nu_in[(size_t)r * 8 + n]);

    #pragma unroll
    for (int s = 0; s < 4; ++s) {
        int j = t + 256 * s;
        float ex = __expf(x[j]);
        float4 a, c;
        {
            float u0 = ex * tn[0], u1 = ex * tn[1], u2 = ex * tn[2], u3 = ex * tn[3];
            a.x = u0 * __builtin_amdgcn_rcpf(1.0f + u0);
            a.y = u1 * __builtin_amdgcn_rcpf(1.0f + u1);
            a.z = u2 * __builtin_amdgcn_rcpf(1.0f + u2);
            a.w = u3 * __builtin_amdgcn_rcpf(1.0f + u3);
        }
        {
            float u0 = ex * tn[4], u1 = ex * tn[5], u2 = ex * tn[6], u3 = ex * tn[7];
            c.x = u0 * __builtin_amdgcn_rcpf(1.0f + u0);
            c.y = u1 * __builtin_amdgcn_rcpf(1.0f + u1);
            c.z = u2 * __builtin_amdgcn_rcpf(1.0f + u2);
            c.w = u3 * __builtin_amdgcn_rcpf(1.0f + u3);
        }
        *(float4*)&pA[j][0] = a;
        *(float4*)&pB[j][0] = c;
    }
    __syncthreads();

    // wave w: j in [256w, 256w+256), lane = d, all 8 heads
    int jbase = wave * 256;
    const float* vbase = qkv + ((size_t)b * SEQ + jbase) * QKV3 + 2 * DIM_HEAD + lane;
    float acc[8] = {};
    #pragma unroll 4
    for (int jj = 0; jj < 256; ++jj) {
        float v = vbase[(size_t)jj * QKV3];
        float4 a = *(const float4*)&pA[jbase + jj][0];
        float4 c = *(const float4*)&pB[jbase + jj][0];
        acc[0] = fmaf(a.x, v, acc[0]);
        acc[1] = fmaf(a.y, v, acc[1]);
        acc[2] = fmaf(a.z, v, acc[2]);
        acc[3] = fmaf(a.w, v, acc[3]);
        acc[4] = fmaf(c.x, v, acc[4]);
        acc[5] = fmaf(c.y, v, acc[5]);
        acc[6] = fmaf(c.z, v, acc[6]);
        acc[7] = fmaf(c.w, v, acc[7]);
    }
    #pragma unroll
    for (int n = 0; n < 8; ++n) ow[wave][n][lane] = acc[n];
    __syncthreads();

    // reduce across waves + head differences -> y[r][h*64+d]
    float* yr = y + (size_t)r * (HEADS * DIM_HEAD);
    #pragma unroll
    for (int s = 0; s < 2; ++s) {
        int c = t + 256 * s;
        int h = c >> 6, dd = c & 63;
        float oh = ow[0][h][dd] + ow[1][h][dd] + ow[2][h][dd] + ow[3][h][dd];
        float op = 0.0f;
        if (h) op = ow[0][h - 1][dd] + ow[1][h - 1][dd] + ow[2][h - 1][dd] + ow[3][h - 1][dd];
        yr[c] = oh - op;
    }
}

// ---------------------------------------------------------------------------
extern "C" void kernel_launch(void* const* d_in, const int* in_sizes, int n_in,
                              void* d_out, int out_size, void* d_ws, size_t ws_size,
                              hipStream_t stream)
{
    const float* x       = (const float*)d_in[0];
    const float* ln_g    = (const float*)d_in[1];
    const float* ln_b    = (const float*)d_in[2];
    const float* w_qkv   = (const float*)d_in[3];
    const float* w_out   = (const float*)d_in[4];
    const float* b_out   = (const float*)d_in[5];
    float* out = (float*)d_out;

    // ws: xn[ROWS*DIM] | qkv[ROWS*192] | dots[4M] | nu[ROWS*8]   (~28.5 MB)
    float* xn   = (float*)d_ws;
    float* qkv  = xn + (size_t)ROWS * DIM;
    float* dots = qkv + (size_t)ROWS * QKV3;
    float* nu   = dots + (size_t)Bsz * SEQ * SEQ;
    float* y    = xn;  // reuse (dead after qkv GEMM; rewritten by pv_kernel)

    // 1) LayerNorm
    ln_kernel<<<ROWS, 256, 0, stream>>>(x, ln_g, ln_b, xn);

    // 2) qkv = xn @ w_qkv
    gemm_kernel<0><<<dim3(QKV3 / 64, ROWS / 64, 1), 256, 0, stream>>>(
        xn, w_qkv, qkv, nullptr,
        ROWS, QKV3, DIM, DIM, QKV3, QKV3, 0, 0, 0, 1.0f);

    // 3) dots[b] = 0.125 * q[b] @ k[b]^T
    gemm_kernel<1><<<dim3(SEQ / 64, SEQ / 64, Bsz), 256, 0, stream>>>(
        qkv, qkv + DIM_HEAD, dots, nullptr,
        SEQ, SEQ, DIM_HEAD, QKV3, QKV3, SEQ,
        (long)SEQ * QKV3, (long)SEQ * QKV3, (long)SEQ * SEQ, 0.125f);

    // 4) LML solve (1 wave/row): nu[4096][8]
    solve_kernel<<<ROWS / 4, 256, 0, stream>>>(dots, nu);

    // 5) PV + head differences -> y
    pv_kernel<<<ROWS, 256, 0, stream>>>(dots, nu, qkv, y);

    // 6) out = y @ w_out + b_out
    gemm_kernel<0><<<dim3(DIM / 64, ROWS / 64, 1), 256, 0, stream>>>(
        y, w_out, out, b_out,
        ROWS, DIM, DIM, DIM, DIM, DIM, 0, 0, 0, 1.0f);
}

// Round 6
// 341.720 us; speedup vs baseline: 1.8425x; 1.0590x over previous
//
#include <hip/hip_runtime.h>
#include <hip/hip_bf16.h>

// Problem constants
#define Bsz 4
#define SEQ 1024
#define DIM 512
#define HEADS 8
#define DIM_HEAD 64
#define ROWS (Bsz * SEQ)        // 4096
#define QKV3 (3 * DIM_HEAD)     // 192

// ---------------------------------------------------------------------------
// LayerNorm: one block per row of x [ROWS, 512]
// ---------------------------------------------------------------------------
__global__ __launch_bounds__(256) void ln_kernel(
    const float* __restrict__ x, const float* __restrict__ g,
    const float* __restrict__ beta, float* __restrict__ xn)
{
    int r = blockIdx.x;
    int t = threadIdx.x;
    const float* xr = x + (size_t)r * DIM;
    float v0 = xr[t], v1 = xr[t + 256];
    float s = v0 + v1, ss = v0 * v0 + v1 * v1;
    #pragma unroll
    for (int off = 32; off; off >>= 1) {
        s  += __shfl_xor(s, off);
        ss += __shfl_xor(ss, off);
    }
    __shared__ float rs[4], rss[4];
    int wave = t >> 6, lane = t & 63;
    if (lane == 0) { rs[wave] = s; rss[wave] = ss; }
    __syncthreads();
    s  = rs[0] + rs[1] + rs[2] + rs[3];
    ss = rss[0] + rss[1] + rss[2] + rss[3];
    float mu  = s * (1.0f / DIM);
    float var = ss * (1.0f / DIM) - mu * mu;
    float rstd = rsqrtf(var + 1e-5f);
    float* out = xn + (size_t)r * DIM;
    out[t]       = (v0 - mu) * rstd * g[t]       + beta[t];
    out[t + 256] = (v1 - mu) * rstd * g[t + 256] + beta[t + 256];
}

// ---------------------------------------------------------------------------
// Generic fp32 tiled GEMM: C = alpha * A @ op(B) + bias
// ---------------------------------------------------------------------------
template <int TRANS_B>
__global__ __launch_bounds__(256) void gemm_kernel(
    const float* __restrict__ A, const float* __restrict__ B,
    float* __restrict__ C, const float* __restrict__ bias,
    int M, int N, int K, int lda, int ldb, int ldc,
    long strideA, long strideB, long strideC, float alpha)
{
    int bz = blockIdx.z;
    A += (size_t)bz * strideA;
    B += (size_t)bz * strideB;
    C += (size_t)bz * strideC;

    const int BK = 32;
    __shared__ float As[BK][64 + 1];
    __shared__ float Bs[BK][64 + 1];

    int t = threadIdx.x;
    int block_m = blockIdx.y * 64;
    int block_n = blockIdx.x * 64;
    int tx = t & 15, ty = t >> 4;

    float acc[4][4] = {};

    for (int k0 = 0; k0 < K; k0 += BK) {
        { // A tile 64x32 (row-major src, store transposed)
            int kk = t & 31;
            int m0 = t >> 5;
            #pragma unroll
            for (int s = 0; s < 8; ++s) {
                int m = m0 + s * 8;
                As[kk][m] = A[(size_t)(block_m + m) * lda + k0 + kk];
            }
        }
        if (TRANS_B) {
            int kk = t & 31;
            int n0 = t >> 5;
            #pragma unroll
            for (int s = 0; s < 8; ++s) {
                int n = n0 + s * 8;
                Bs[kk][n] = B[(size_t)(block_n + n) * ldb + k0 + kk];
            }
        } else {
            int n = t & 63;
            int kb = t >> 6;
            #pragma unroll
            for (int s = 0; s < 8; ++s) {
                int kk = kb + s * 4;
                Bs[kk][n] = B[(size_t)(k0 + kk) * ldb + block_n + n];
            }
        }
        __syncthreads();
        #pragma unroll
        for (int kk = 0; kk < BK; ++kk) {
            float a[4], b[4];
            #pragma unroll
            for (int i = 0; i < 4; ++i) a[i] = As[kk][ty * 4 + i];
            #pragma unroll
            for (int j = 0; j < 4; ++j) b[j] = Bs[kk][tx * 4 + j];
            #pragma unroll
            for (int i = 0; i < 4; ++i)
                #pragma unroll
                for (int j = 0; j < 4; ++j) acc[i][j] += a[i] * b[j];
        }
        __syncthreads();
    }

    #pragma unroll
    for (int i = 0; i < 4; ++i) {
        int m = block_m + ty * 4 + i;
        #pragma unroll
        for (int j = 0; j < 4; ++j) {
            int n = block_n + tx * 4 + j;
            float v = acc[i][j] * alpha;
            if (bias) v += bias[n];
            C[(size_t)m * ldc + n] = v;
        }
    }
}

// ---------------------------------------------------------------------------
// LML solve — round-3 proven eval sequence (12 bisection + 5 guarded Newton,
// tight bracket nu* in [logit(N/1024)-mx, logit(N/1024)-mn]), restructured:
//  * TWO waves per row, each solving 4 of the 8 nu's (independent problems,
//    zero cross-wave communication; per-wave serial work halves; 8192 waves
//    for latency hiding).
//  * Pairwise rcp: u1/(1+u1)+u2/(1+u2) = (u1*a2+u2*a1)/(a1*a2) -> one
//    v_rcp per element PAIR. In Newton, inv1=r*a2=1/a1 recovers both
//    reciprocals and p(1-p) = p*inv exactly. Same eval sequence/decisions.
// ---------------------------------------------------------------------------
__global__ __launch_bounds__(256) void solve_kernel(
    const float* __restrict__ dots, float* __restrict__ nu_out)
{
    int wave = threadIdx.x >> 6;
    int lane = threadIdx.x & 63;
    int r = blockIdx.x * 2 + (wave >> 1);
    int nbase = (wave & 1) * 4;          // this wave solves N = nbase+1 .. nbase+4
    const float* x = dots + (size_t)r * SEQ;

    float e[16];
    #pragma unroll
    for (int s = 0; s < 4; ++s) {
        float4 v = *(const float4*)(x + lane * 4 + 256 * s);
        e[4 * s + 0] = v.x; e[4 * s + 1] = v.y;
        e[4 * s + 2] = v.z; e[4 * s + 3] = v.w;
    }
    float mx = e[0], mn = e[0];
    #pragma unroll
    for (int s = 1; s < 16; ++s) { mx = fmaxf(mx, e[s]); mn = fminf(mn, e[s]); }
    #pragma unroll
    for (int off = 32; off; off >>= 1) {
        mx = fmaxf(mx, __shfl_xor(mx, off));
        mn = fminf(mn, __shfl_xor(mn, off));
    }
    #pragma unroll
    for (int s = 0; s < 16; ++s) e[s] = __expf(e[s]);

    float lo[4], hi[4], Nf[4];
    #pragma unroll
    for (int k = 0; k < 4; ++k) {
        int N = nbase + k + 1;
        Nf[k] = (float)N;
        float lgt = __logf((float)N / (float)(SEQ - N));
        lo[k] = lgt - mx;
        hi[k] = lgt - mn;
    }

    // ---- 12 bisection iterations ----
    for (int it = 0; it < 12; ++it) {
        float S[4];
        #pragma unroll
        for (int k = 0; k < 4; ++k) {
            float mid = 0.5f * (lo[k] + hi[k]);
            float tn = __expf(mid);
            float sn = 0.0f;
            #pragma unroll
            for (int s = 0; s < 8; ++s) {
                float u1 = e[2 * s] * tn, u2 = e[2 * s + 1] * tn;
                float a1 = 1.0f + u1, a2 = 1.0f + u2;
                float rr = __builtin_amdgcn_rcpf(a1 * a2);
                float num = fmaf(u1, a2, u2 * a1);
                sn = fmaf(num, rr, sn);
            }
            S[k] = sn;
        }
        #pragma unroll
        for (int k = 0; k < 4; ++k) {
            #pragma unroll
            for (int off = 32; off; off >>= 1) S[k] += __shfl_xor(S[k], off);
            float mid = 0.5f * (lo[k] + hi[k]);
            if (S[k] < Nf[k]) lo[k] = mid; else hi[k] = mid;
        }
    }

    float nu[4];
    #pragma unroll
    for (int k = 0; k < 4; ++k) nu[k] = 0.5f * (lo[k] + hi[k]);

    // ---- 5 guarded Newton iterations ----
    for (int it = 0; it < 5; ++it) {
        float S[4], Sp[4];
        #pragma unroll
        for (int k = 0; k < 4; ++k) {
            float tn = __expf(nu[k]);
            float sn = 0.0f, spn = 0.0f;
            #pragma unroll
            for (int s = 0; s < 8; ++s) {
                float u1 = e[2 * s] * tn, u2 = e[2 * s + 1] * tn;
                float a1 = 1.0f + u1, a2 = 1.0f + u2;
                float rr = __builtin_amdgcn_rcpf(a1 * a2);
                float inv1 = rr * a2, inv2 = rr * a1;     // = 1/a1, 1/a2
                float p1 = u1 * inv1, p2 = u2 * inv2;
                sn += p1 + p2;
                spn = fmaf(p1, inv1, spn);                // p(1-p) = p*inv
                spn = fmaf(p2, inv2, spn);
            }
            S[k] = sn; Sp[k] = spn;
        }
        #pragma unroll
        for (int k = 0; k < 4; ++k) {
            #pragma unroll
            for (int off = 32; off; off >>= 1) {
                S[k]  += __shfl_xor(S[k], off);
                Sp[k] += __shfl_xor(Sp[k], off);
            }
            if (S[k] < Nf[k]) lo[k] = nu[k]; else hi[k] = nu[k];
            float step = (Nf[k] - S[k]) * __builtin_amdgcn_rcpf(Sp[k]);
            float cand = nu[k] + step;
            if (!(cand > lo[k] && cand < hi[k])) cand = 0.5f * (lo[k] + hi[k]);
            nu[k] = cand;
        }
    }

    // lanes 0..3 write this wave's 4 nus (all lanes hold identical values)
    float myv = nu[0];
    #pragma unroll
    for (int k = 1; k < 4; ++k) if (lane == k) myv = nu[k];
    if (lane < 4) nu_out[(size_t)r * 8 + nbase + lane] = myv;
}

// ---------------------------------------------------------------------------
// PV: one block per row. p stored pA[j][0..3] / pB[j][0..3]; inner loop does
// 2 uniform (broadcast) float4 LDS reads per j. Wave w covers j in
// [256w, 256w+256) for ALL 8 heads -> V loaded exactly once per block.
// ---------------------------------------------------------------------------
__global__ __launch_bounds__(256) void pv_kernel(
    const float* __restrict__ dots, const float* __restrict__ nu_in,
    const float* __restrict__ qkv, float* __restrict__ y)
{
    int r = blockIdx.x;
    int b = r >> 10;
    int t = threadIdx.x;
    int wave = t >> 6, lane = t & 63;

    __shared__ float pA[1024][4];     // heads 0..3   16 KB
    __shared__ float pB[1024][4];     // heads 4..7   16 KB
    __shared__ float ow[4][8][64];    // per-wave partials  8 KB

    const float* x = dots + (size_t)r * SEQ;

    float tn[8];
    #pragma unroll
    for (int n = 0; n < 8; ++n) tn[n] = __expf(nu_in[(size_t)r * 8 + n]);

    #pragma unroll
    for (int s = 0; s < 4; ++s) {
        int j = t + 256 * s;
        float ex = __expf(x[j]);
        float4 a, c;
        {
            float u0 = ex * tn[0], u1 = ex * tn[1], u2 = ex * tn[2], u3 = ex * tn[3];
            a.x = u0 * __builtin_amdgcn_rcpf(1.0f + u0);
            a.y = u1 * __builtin_amdgcn_rcpf(1.0f + u1);
            a.z = u2 * __builtin_amdgcn_rcpf(1.0f + u2);
            a.w = u3 * __builtin_amdgcn_rcpf(1.0f + u3);
        }
        {
            float u0 = ex * tn[4], u1 = ex * tn[5], u2 = ex * tn[6], u3 = ex * tn[7];
            c.x = u0 * __builtin_amdgcn_rcpf(1.0f + u0);
            c.y = u1 * __builtin_amdgcn_rcpf(1.0f + u1);
            c.z = u2 * __builtin_amdgcn_rcpf(1.0f + u2);
            c.w = u3 * __builtin_amdgcn_rcpf(1.0f + u3);
        }
        *(float4*)&pA[j][0] = a;
        *(float4*)&pB[j][0] = c;
    }
    __syncthreads();

    // wave w: j in [256w, 256w+256), lane = d, all 8 heads
    int jbase = wave * 256;
    const float* vbase = qkv + ((size_t)b * SEQ + jbase) * QKV3 + 2 * DIM_HEAD + lane;
    float acc[8] = {};
    #pragma unroll 4
    for (int jj = 0; jj < 256; ++jj) {
        float v = vbase[(size_t)jj * QKV3];
        float4 a = *(const float4*)&pA[jbase + jj][0];
        float4 c = *(const float4*)&pB[jbase + jj][0];
        acc[0] = fmaf(a.x, v, acc[0]);
        acc[1] = fmaf(a.y, v, acc[1]);
        acc[2] = fmaf(a.z, v, acc[2]);
        acc[3] = fmaf(a.w, v, acc[3]);
        acc[4] = fmaf(c.x, v, acc[4]);
        acc[5] = fmaf(c.y, v, acc[5]);
        acc[6] = fmaf(c.z, v, acc[6]);
        acc[7] = fmaf(c.w, v, acc[7]);
    }
    #pragma unroll
    for (int n = 0; n < 8; ++n) ow[wave][n][lane] = acc[n];
    __syncthreads();

    // reduce across waves + head differences -> y[r][h*64+d]
    float* yr = y + (size_t)r * (HEADS * DIM_HEAD);
    #pragma unroll
    for (int s = 0; s < 2; ++s) {
        int c = t + 256 * s;
        int h = c >> 6, dd = c & 63;
        float oh = ow[0][h][dd] + ow[1][h][dd] + ow[2][h][dd] + ow[3][h][dd];
        float op = 0.0f;
        if (h) op = ow[0][h - 1][dd] + ow[1][h - 1][dd] + ow[2][h - 1][dd] + ow[3][h - 1][dd];
        yr[c] = oh - op;
    }
}

// ---------------------------------------------------------------------------
extern "C" void kernel_launch(void* const* d_in, const int* in_sizes, int n_in,
                              void* d_out, int out_size, void* d_ws, size_t ws_size,
                              hipStream_t stream)
{
    const float* x       = (const float*)d_in[0];
    const float* ln_g    = (const float*)d_in[1];
    const float* ln_b    = (const float*)d_in[2];
    const float* w_qkv   = (const float*)d_in[3];
    const float* w_out   = (const float*)d_in[4];
    const float* b_out   = (const float*)d_in[5];
    float* out = (float*)d_out;

    // ws: xn[ROWS*DIM] | qkv[ROWS*192] | dots[4M] | nu[ROWS*8]   (~28.5 MB)
    float* xn   = (float*)d_ws;
    float* qkv  = xn + (size_t)ROWS * DIM;
    float* dots = qkv + (size_t)ROWS * QKV3;
    float* nu   = dots + (size_t)Bsz * SEQ * SEQ;
    float* y    = xn;  // reuse (dead after qkv GEMM; rewritten by pv_kernel)

    // 1) LayerNorm
    ln_kernel<<<ROWS, 256, 0, stream>>>(x, ln_g, ln_b, xn);

    // 2) qkv = xn @ w_qkv
    gemm_kernel<0><<<dim3(QKV3 / 64, ROWS / 64, 1), 256, 0, stream>>>(
        xn, w_qkv, qkv, nullptr,
        ROWS, QKV3, DIM, DIM, QKV3, QKV3, 0, 0, 0, 1.0f);

    // 3) dots[b] = 0.125 * q[b] @ k[b]^T
    gemm_kernel<1><<<dim3(SEQ / 64, SEQ / 64, Bsz), 256, 0, stream>>>(
        qkv, qkv + DIM_HEAD, dots, nullptr,
        SEQ, SEQ, DIM_HEAD, QKV3, QKV3, SEQ,
        (long)SEQ * QKV3, (long)SEQ * QKV3, (long)SEQ * SEQ, 0.125f);

    // 4) LML solve (2 waves/row, 4 nu each): nu[4096][8]
    solve_kernel<<<ROWS / 2, 256, 0, stream>>>(dots, nu);

    // 5) PV + head differences -> y
    pv_kernel<<<ROWS, 256, 0, stream>>>(dots, nu, qkv, y);

    // 6) out = y @ w_out + b_out
    gemm_kernel<0><<<dim3(DIM / 64, ROWS / 64, 1), 256, 0, stream>>>(
        y, w_out, out, b_out,
        ROWS, DIM, DIM, DIM, DIM, DIM, 0, 0, 0, 1.0f);
}

// Round 7
// 292.752 us; speedup vs baseline: 2.1507x; 1.1673x over previous
//
#include <hip/hip_runtime.h>
#include <hip/hip_bf16.h>

// Problem constants
#define Bsz 4
#define SEQ 1024
#define DIM 512
#define HEADS 8
#define DIM_HEAD 64
#define ROWS (Bsz * SEQ)        // 4096
#define QKV3 (3 * DIM_HEAD)     // 192

typedef _Float16 f16x4 __attribute__((ext_vector_type(4)));
typedef float f32x4 __attribute__((ext_vector_type(4)));

// ---------------------------------------------------------------------------
// LayerNorm: one block per row of x [ROWS, 512]  (unchanged)
// ---------------------------------------------------------------------------
__global__ __launch_bounds__(256) void ln_kernel(
    const float* __restrict__ x, const float* __restrict__ g,
    const float* __restrict__ beta, float* __restrict__ xn)
{
    int r = blockIdx.x;
    int t = threadIdx.x;
    const float* xr = x + (size_t)r * DIM;
    float v0 = xr[t], v1 = xr[t + 256];
    float s = v0 + v1, ss = v0 * v0 + v1 * v1;
    #pragma unroll
    for (int off = 32; off; off >>= 1) {
        s  += __shfl_xor(s, off);
        ss += __shfl_xor(ss, off);
    }
    __shared__ float rs[4], rss[4];
    int wave = t >> 6, lane = t & 63;
    if (lane == 0) { rs[wave] = s; rss[wave] = ss; }
    __syncthreads();
    s  = rs[0] + rs[1] + rs[2] + rs[3];
    ss = rss[0] + rss[1] + rss[2] + rss[3];
    float mu  = s * (1.0f / DIM);
    float var = ss * (1.0f / DIM) - mu * mu;
    float rstd = rsqrtf(var + 1e-5f);
    float* out = xn + (size_t)r * DIM;
    out[t]       = (v0 - mu) * rstd * g[t]       + beta[t];
    out[t + 256] = (v1 - mu) * rstd * g[t + 256] + beta[t + 256];
}

// ---------------------------------------------------------------------------
// fp16-MFMA GEMM: C = alpha * A @ op(B) + bias. fp32 globals; staging
// converts to fp16 in LDS; v_mfma_f32_16x16x16f16 accumulates in fp32.
// BM=BN=64, BK=32, 256 threads = 4 waves in 2x2; each wave: 2x2 16x16 tiles.
// LDS row stride 36 halves: fragment b64 reads conflict-free (18m mod 32
// distinct over 16 lanes). Layouts (CDNA documented, m89-consistent):
//   A: row=l&15, k=4*(l>>4)+i   B: col=l&15, k=4*(l>>4)+i
//   D: col=l&15, row=4*(l>>4)+i
// TRANS_B=1: C[m][n] = sum_k A[m][k]*B[n][k]
// ---------------------------------------------------------------------------
template <int TRANS_B>
__global__ __launch_bounds__(256) void gemm16_kernel(
    const float* __restrict__ A, const float* __restrict__ B,
    float* __restrict__ C, const float* __restrict__ bias,
    int K, int lda, int ldb, int ldc,
    long strideA, long strideB, long strideC, float alpha)
{
    int bz = blockIdx.z;
    A += (size_t)bz * strideA;
    B += (size_t)bz * strideB;
    C += (size_t)bz * strideC;

    __shared__ _Float16 As[64][36];
    __shared__ _Float16 Bs[64][36];

    int t = threadIdx.x;
    int block_m = blockIdx.y * 64;
    int block_n = blockIdx.x * 64;
    int wave = t >> 6, lane = t & 63;
    int wm = wave >> 1, wn = wave & 1;
    int lrow = lane & 15, g = lane >> 4;

    int sm = t & 63;   // staging row (m or n)
    int kc = t >> 6;   // staging k-chunk of 8

    f32x4 acc[2][2] = {};

    for (int k0 = 0; k0 < K; k0 += 32) {
        { // A tile: rows sm, k = k0 + kc*8 .. +8 (row-major, float4 aligned)
            const float4* pa = reinterpret_cast<const float4*>(
                A + (size_t)(block_m + sm) * lda + k0 + kc * 8);
            float4 a0 = pa[0], a1 = pa[1];
            f16x4 h0 = { (_Float16)a0.x, (_Float16)a0.y, (_Float16)a0.z, (_Float16)a0.w };
            f16x4 h1 = { (_Float16)a1.x, (_Float16)a1.y, (_Float16)a1.z, (_Float16)a1.w };
            *(f16x4*)&As[sm][kc * 8]     = h0;
            *(f16x4*)&As[sm][kc * 8 + 4] = h1;
        }
        if (TRANS_B) { // B[n][k] row-major
            const float4* pb = reinterpret_cast<const float4*>(
                B + (size_t)(block_n + sm) * ldb + k0 + kc * 8);
            float4 b0 = pb[0], b1 = pb[1];
            f16x4 h0 = { (_Float16)b0.x, (_Float16)b0.y, (_Float16)b0.z, (_Float16)b0.w };
            f16x4 h1 = { (_Float16)b1.x, (_Float16)b1.y, (_Float16)b1.z, (_Float16)b1.w };
            *(f16x4*)&Bs[sm][kc * 8]     = h0;
            *(f16x4*)&Bs[sm][kc * 8 + 4] = h1;
        } else {       // B[k][n] row-major: 8 per-k coalesced-across-lanes loads
            const float* pb = B + (size_t)(k0 + kc * 8) * ldb + block_n + sm;
            float b[8];
            #pragma unroll
            for (int i = 0; i < 8; ++i) b[i] = pb[(size_t)i * ldb];
            f16x4 h0 = { (_Float16)b[0], (_Float16)b[1], (_Float16)b[2], (_Float16)b[3] };
            f16x4 h1 = { (_Float16)b[4], (_Float16)b[5], (_Float16)b[6], (_Float16)b[7] };
            *(f16x4*)&Bs[sm][kc * 8]     = h0;
            *(f16x4*)&Bs[sm][kc * 8 + 4] = h1;
        }
        __syncthreads();
        #pragma unroll
        for (int ks = 0; ks < 2; ++ks) {
            f16x4 a0 = *(const f16x4*)&As[32 * wm + lrow][ks * 16 + g * 4];
            f16x4 a1 = *(const f16x4*)&As[32 * wm + 16 + lrow][ks * 16 + g * 4];
            f16x4 b0 = *(const f16x4*)&Bs[32 * wn + lrow][ks * 16 + g * 4];
            f16x4 b1 = *(const f16x4*)&Bs[32 * wn + 16 + lrow][ks * 16 + g * 4];
            acc[0][0] = __builtin_amdgcn_mfma_f32_16x16x16f16(a0, b0, acc[0][0], 0, 0, 0);
            acc[0][1] = __builtin_amdgcn_mfma_f32_16x16x16f16(a0, b1, acc[0][1], 0, 0, 0);
            acc[1][0] = __builtin_amdgcn_mfma_f32_16x16x16f16(a1, b0, acc[1][0], 0, 0, 0);
            acc[1][1] = __builtin_amdgcn_mfma_f32_16x16x16f16(a1, b1, acc[1][1], 0, 0, 0);
        }
        __syncthreads();
    }

    #pragma unroll
    for (int mt = 0; mt < 2; ++mt)
        #pragma unroll
        for (int nt = 0; nt < 2; ++nt) {
            int n = block_n + 32 * wn + 16 * nt + lrow;
            float bv = bias ? bias[n] : 0.0f;
            #pragma unroll
            for (int i = 0; i < 4; ++i) {
                int m = block_m + 32 * wm + 16 * mt + g * 4 + i;
                C[(size_t)m * ldc + n] = acc[mt][nt][i] * alpha + bv;
            }
        }
}

// ---------------------------------------------------------------------------
// LML solve (unchanged from round 6): 2 waves/row, 4 nu each; tight bracket;
// 12 bisection + 5 guarded Newton; pairwise rcp.
// ---------------------------------------------------------------------------
__global__ __launch_bounds__(256) void solve_kernel(
    const float* __restrict__ dots, float* __restrict__ nu_out)
{
    int wave = threadIdx.x >> 6;
    int lane = threadIdx.x & 63;
    int r = blockIdx.x * 2 + (wave >> 1);
    int nbase = (wave & 1) * 4;
    const float* x = dots + (size_t)r * SEQ;

    float e[16];
    #pragma unroll
    for (int s = 0; s < 4; ++s) {
        float4 v = *(const float4*)(x + lane * 4 + 256 * s);
        e[4 * s + 0] = v.x; e[4 * s + 1] = v.y;
        e[4 * s + 2] = v.z; e[4 * s + 3] = v.w;
    }
    float mx = e[0], mn = e[0];
    #pragma unroll
    for (int s = 1; s < 16; ++s) { mx = fmaxf(mx, e[s]); mn = fminf(mn, e[s]); }
    #pragma unroll
    for (int off = 32; off; off >>= 1) {
        mx = fmaxf(mx, __shfl_xor(mx, off));
        mn = fminf(mn, __shfl_xor(mn, off));
    }
    #pragma unroll
    for (int s = 0; s < 16; ++s) e[s] = __expf(e[s]);

    float lo[4], hi[4], Nf[4];
    #pragma unroll
    for (int k = 0; k < 4; ++k) {
        int N = nbase + k + 1;
        Nf[k] = (float)N;
        float lgt = __logf((float)N / (float)(SEQ - N));
        lo[k] = lgt - mx;
        hi[k] = lgt - mn;
    }

    for (int it = 0; it < 12; ++it) {
        float S[4];
        #pragma unroll
        for (int k = 0; k < 4; ++k) {
            float mid = 0.5f * (lo[k] + hi[k]);
            float tn = __expf(mid);
            float sn = 0.0f;
            #pragma unroll
            for (int s = 0; s < 8; ++s) {
                float u1 = e[2 * s] * tn, u2 = e[2 * s + 1] * tn;
                float a1 = 1.0f + u1, a2 = 1.0f + u2;
                float rr = __builtin_amdgcn_rcpf(a1 * a2);
                float num = fmaf(u1, a2, u2 * a1);
                sn = fmaf(num, rr, sn);
            }
            S[k] = sn;
        }
        #pragma unroll
        for (int k = 0; k < 4; ++k) {
            #pragma unroll
            for (int off = 32; off; off >>= 1) S[k] += __shfl_xor(S[k], off);
            float mid = 0.5f * (lo[k] + hi[k]);
            if (S[k] < Nf[k]) lo[k] = mid; else hi[k] = mid;
        }
    }

    float nu[4];
    #pragma unroll
    for (int k = 0; k < 4; ++k) nu[k] = 0.5f * (lo[k] + hi[k]);

    for (int it = 0; it < 5; ++it) {
        float S[4], Sp[4];
        #pragma unroll
        for (int k = 0; k < 4; ++k) {
            float tn = __expf(nu[k]);
            float sn = 0.0f, spn = 0.0f;
            #pragma unroll
            for (int s = 0; s < 8; ++s) {
                float u1 = e[2 * s] * tn, u2 = e[2 * s + 1] * tn;
                float a1 = 1.0f + u1, a2 = 1.0f + u2;
                float rr = __builtin_amdgcn_rcpf(a1 * a2);
                float inv1 = rr * a2, inv2 = rr * a1;
                float p1 = u1 * inv1, p2 = u2 * inv2;
                sn += p1 + p2;
                spn = fmaf(p1, inv1, spn);
                spn = fmaf(p2, inv2, spn);
            }
            S[k] = sn; Sp[k] = spn;
        }
        #pragma unroll
        for (int k = 0; k < 4; ++k) {
            #pragma unroll
            for (int off = 32; off; off >>= 1) {
                S[k]  += __shfl_xor(S[k], off);
                Sp[k] += __shfl_xor(Sp[k], off);
            }
            if (S[k] < Nf[k]) lo[k] = nu[k]; else hi[k] = nu[k];
            float step = (Nf[k] - S[k]) * __builtin_amdgcn_rcpf(Sp[k]);
            float cand = nu[k] + step;
            if (!(cand > lo[k] && cand < hi[k])) cand = 0.5f * (lo[k] + hi[k]);
            nu[k] = cand;
        }
    }

    float myv = nu[0];
    #pragma unroll
    for (int k = 1; k < 4; ++k) if (lane == k) myv = nu[k];
    if (lane < 4) nu_out[(size_t)r * 8 + nbase + lane] = myv;
}

// ---------------------------------------------------------------------------
// PV (unchanged from round 6)
// ---------------------------------------------------------------------------
__global__ __launch_bounds__(256) void pv_kernel(
    const float* __restrict__ dots, const float* __restrict__ nu_in,
    const float* __restrict__ qkv, float* __restrict__ y)
{
    int r = blockIdx.x;
    int b = r >> 10;
    int t = threadIdx.x;
    int wave = t >> 6, lane = t & 63;

    __shared__ float pA[1024][4];
    __shared__ float pB[1024][4];
    __shared__ float ow[4][8][64];

    const float* x = dots + (size_t)r * SEQ;

    float tn[8];
    #pragma unroll
    for (int n = 0; n < 8; ++n) tn[n] = __expf(nu_in[(size_t)r * 8 + n]);

    #pragma unroll
    for (int s = 0; s < 4; ++s) {
        int j = t + 256 * s;
        float ex = __expf(x[j]);
        float4 a, c;
        {
            float u0 = ex * tn[0], u1 = ex * tn[1], u2 = ex * tn[2], u3 = ex * tn[3];
            a.x = u0 * __builtin_amdgcn_rcpf(1.0f + u0);
            a.y = u1 * __builtin_amdgcn_rcpf(1.0f + u1);
            a.z = u2 * __builtin_amdgcn_rcpf(1.0f + u2);
            a.w = u3 * __builtin_amdgcn_rcpf(1.0f + u3);
        }
        {
            float u0 = ex * tn[4], u1 = ex * tn[5], u2 = ex * tn[6], u3 = ex * tn[7];
            c.x = u0 * __builtin_amdgcn_rcpf(1.0f + u0);
            c.y = u1 * __builtin_amdgcn_rcpf(1.0f + u1);
            c.z = u2 * __builtin_amdgcn_rcpf(1.0f + u2);
            c.w = u3 * __builtin_amdgcn_rcpf(1.0f + u3);
        }
        *(float4*)&pA[j][0] = a;
        *(float4*)&pB[j][0] = c;
    }
    __syncthreads();

    int jbase = wave * 256;
    const float* vbase = qkv + ((size_t)b * SEQ + jbase) * QKV3 + 2 * DIM_HEAD + lane;
    float acc[8] = {};
    #pragma unroll 4
    for (int jj = 0; jj < 256; ++jj) {
        float v = vbase[(size_t)jj * QKV3];
        float4 a = *(const float4*)&pA[jbase + jj][0];
        float4 c = *(const float4*)&pB[jbase + jj][0];
        acc[0] = fmaf(a.x, v, acc[0]);
        acc[1] = fmaf(a.y, v, acc[1]);
        acc[2] = fmaf(a.z, v, acc[2]);
        acc[3] = fmaf(a.w, v, acc[3]);
        acc[4] = fmaf(c.x, v, acc[4]);
        acc[5] = fmaf(c.y, v, acc[5]);
        acc[6] = fmaf(c.z, v, acc[6]);
        acc[7] = fmaf(c.w, v, acc[7]);
    }
    #pragma unroll
    for (int n = 0; n < 8; ++n) ow[wave][n][lane] = acc[n];
    __syncthreads();

    float* yr = y + (size_t)r * (HEADS * DIM_HEAD);
    #pragma unroll
    for (int s = 0; s < 2; ++s) {
        int c = t + 256 * s;
        int h = c >> 6, dd = c & 63;
        float oh = ow[0][h][dd] + ow[1][h][dd] + ow[2][h][dd] + ow[3][h][dd];
        float op = 0.0f;
        if (h) op = ow[0][h - 1][dd] + ow[1][h - 1][dd] + ow[2][h - 1][dd] + ow[3][h - 1][dd];
        yr[c] = oh - op;
    }
}

// ---------------------------------------------------------------------------
extern "C" void kernel_launch(void* const* d_in, const int* in_sizes, int n_in,
                              void* d_out, int out_size, void* d_ws, size_t ws_size,
                              hipStream_t stream)
{
    const float* x       = (const float*)d_in[0];
    const float* ln_g    = (const float*)d_in[1];
    const float* ln_b    = (const float*)d_in[2];
    const float* w_qkv   = (const float*)d_in[3];
    const float* w_out   = (const float*)d_in[4];
    const float* b_out   = (const float*)d_in[5];
    float* out = (float*)d_out;

    // ws: xn[ROWS*DIM] | qkv[ROWS*192] | dots[4M] | nu[ROWS*8]   (~28.5 MB)
    float* xn   = (float*)d_ws;
    float* qkv  = xn + (size_t)ROWS * DIM;
    float* dots = qkv + (size_t)ROWS * QKV3;
    float* nu   = dots + (size_t)Bsz * SEQ * SEQ;
    float* y    = xn;  // reuse (dead after qkv GEMM; rewritten by pv_kernel)

    // 1) LayerNorm
    ln_kernel<<<ROWS, 256, 0, stream>>>(x, ln_g, ln_b, xn);

    // 2) qkv = xn @ w_qkv   [4096,512]x[512,192]
    gemm16_kernel<0><<<dim3(QKV3 / 64, ROWS / 64, 1), 256, 0, stream>>>(
        xn, w_qkv, qkv, nullptr,
        DIM, DIM, QKV3, QKV3, 0, 0, 0, 1.0f);

    // 3) dots[b] = 0.125 * q[b] @ k[b]^T   batched [1024,64]x[64,1024]
    gemm16_kernel<1><<<dim3(SEQ / 64, SEQ / 64, Bsz), 256, 0, stream>>>(
        qkv, qkv + DIM_HEAD, dots, nullptr,
        DIM_HEAD, QKV3, QKV3, SEQ,
        (long)SEQ * QKV3, (long)SEQ * QKV3, (long)SEQ * SEQ, 0.125f);

    // 4) LML solve (2 waves/row, 4 nu each): nu[4096][8]
    solve_kernel<<<ROWS / 2, 256, 0, stream>>>(dots, nu);

    // 5) PV + head differences -> y
    pv_kernel<<<ROWS, 256, 0, stream>>>(dots, nu, qkv, y);

    // 6) out = y @ w_out + b_out   [4096,512]x[512,512]
    gemm16_kernel<0><<<dim3(DIM / 64, ROWS / 64, 1), 256, 0, stream>>>(
        y, w_out, out, b_out,
        DIM, DIM, DIM, DIM, 0, 0, 0, 1.0f);
}